// Round 3
// baseline (1132.729 us; speedup 1.0000x reference)
//
#include <hip/hip_runtime.h>
#include <hip/hip_bf16.h>
#include <math.h>

// GraphSAGE 2-layer inference, f32.
// Split design: gather_mean (latency-hidden streaming) materializes the
// neighbor-mean; sage_dense does the GEMM with coalesced agg reads and a
// cheap fused self-gather. Fused single-kernel path kept as ws fallback.

#define F    128
#define KNB  10
#define BM   32

// W [128][256] row-major  ->  WT [256][128] row-major
__global__ __launch_bounds__(256) void transpose_w(const float* __restrict__ W,
                                                   float* __restrict__ WT) {
    int e = blockIdx.x * 256 + threadIdx.x;   // 0 .. 32767
    int o = e >> 8;      // 0..127
    int j = e & 255;     // 0..255
    WT[j * F + o] = W[e];
}

// agg[row][:] = mean_k feats[nidx[row][k]][:]   (with isnan -> 0.5 parity)
// 8 rows/block, 32 lanes/row (float4 each). All 10 gathers issued in-flight.
__global__ __launch_bounds__(256) void gather_mean(
    const float* __restrict__ feats,      // [nsrc][128]
    const int*   __restrict__ neighIdx,   // [nrows][10]
    float*       __restrict__ agg,        // [nrows][128]
    int nrows)
{
    const int t    = threadIdx.x;
    const int row  = blockIdx.x * 8 + (t >> 5);
    const int lane = t & 31;
    if (row >= nrows) return;

    const int* nb = neighIdx + (size_t)row * KNB;
    int n0 = nb[0], n1 = nb[1], n2 = nb[2], n3 = nb[3], n4 = nb[4];
    int n5 = nb[5], n6 = nb[6], n7 = nb[7], n8 = nb[8], n9 = nb[9];

    const size_t c = (size_t)lane * 4;
    float4 v0 = *(const float4*)(feats + (size_t)n0 * F + c);
    float4 v1 = *(const float4*)(feats + (size_t)n1 * F + c);
    float4 v2 = *(const float4*)(feats + (size_t)n2 * F + c);
    float4 v3 = *(const float4*)(feats + (size_t)n3 * F + c);
    float4 v4 = *(const float4*)(feats + (size_t)n4 * F + c);
    float4 v5 = *(const float4*)(feats + (size_t)n5 * F + c);
    float4 v6 = *(const float4*)(feats + (size_t)n6 * F + c);
    float4 v7 = *(const float4*)(feats + (size_t)n7 * F + c);
    float4 v8 = *(const float4*)(feats + (size_t)n8 * F + c);
    float4 v9 = *(const float4*)(feats + (size_t)n9 * F + c);

    float4 s;
    s.x = ((v0.x + v1.x) + (v2.x + v3.x)) + ((v4.x + v5.x) + (v6.x + v7.x)) + (v8.x + v9.x);
    s.y = ((v0.y + v1.y) + (v2.y + v3.y)) + ((v4.y + v5.y) + (v6.y + v7.y)) + (v8.y + v9.y);
    s.z = ((v0.z + v1.z) + (v2.z + v3.z)) + ((v4.z + v5.z) + (v6.z + v7.z)) + (v8.z + v9.z);
    s.w = ((v0.w + v1.w) + (v2.w + v3.w)) + ((v4.w + v5.w) + (v6.w + v7.w)) + (v8.w + v9.w);
    const float inv = 1.0f / (float)KNB;
    s.x *= inv; s.y *= inv; s.z *= inv; s.w *= inv;
    if (isnan(s.x)) s.x = 0.5f;
    if (isnan(s.y)) s.y = 0.5f;
    if (isnan(s.z)) s.z = 0.5f;
    if (isnan(s.w)) s.w = 0.5f;

    *(float4*)(agg + (size_t)row * F + c) = s;
}

// out[r][o] = relu6( sum_j [self | agg][r][j] * WT[j][o] )
// Self half gathered (1 load/thread/kk); agg half read coalesced.
__global__ __launch_bounds__(256) void sage_dense(
    const float* __restrict__ feats,     // self source [nsrc][128]
    const float* __restrict__ agg,       // [nrows][128] precomputed mean
    const float* __restrict__ WT,        // [256][128]
    const int*   __restrict__ selfIdx,   // [nrows]
    float*       __restrict__ out,       // [nrows][128]
    int nrows)
{
    __shared__ float Xs[BM][68];         // 64-col K-chunk of combined X
    __shared__ float Ws[64][132];        // WT chunk
    __shared__ int   sidx[BM];

    const int t  = threadIdx.x;
    const int r0 = blockIdx.x * BM;

    if (t < BM) sidx[t] = selfIdx[r0 + t];

    const int ct = (t >> 6) * 8 + (t & 7);   // col group
    const int rt = (t >> 3) & 7;             // row group: rows rt, rt+8, rt+16, rt+24

    const int grow = t >> 4;             // stage: row (0..15), second row = +16
    const int gc4  = t & 15;             // stage: float4 slot within 64-col chunk

    float4 acc[4];
    #pragma unroll
    for (int i = 0; i < 4; ++i) acc[i] = make_float4(0.f, 0.f, 0.f, 0.f);

    for (int kk = 0; kk < 4; ++kk) {
        __syncthreads();

        // stage WT chunk
        {
            const float4* src = (const float4*)(WT + (size_t)kk * 64 * F);
            #pragma unroll
            for (int it = 0; it < 8; ++it) {
                int e4 = t + it * 256;
                int jj = e4 >> 5;
                int o4 = e4 & 31;
                *(float4*)&Ws[jj][o4 * 4] = src[e4];
            }
        }

        // stage X chunk
        if (kk < 2) {
            #pragma unroll
            for (int half = 0; half < 2; ++half) {
                int row = grow + half * 16;
                const float4* src =
                    (const float4*)(feats + (size_t)sidx[row] * F + kk * 64);
                *(float4*)&Xs[row][gc4 * 4] = src[gc4];
            }
        } else {
            #pragma unroll
            for (int half = 0; half < 2; ++half) {
                int row = grow + half * 16;
                const float4* src =
                    (const float4*)(agg + (size_t)(r0 + row) * F + (kk - 2) * 64);
                *(float4*)&Xs[row][gc4 * 4] = src[gc4];
            }
        }
        __syncthreads();

        // register-blocked GEMM: 4 rows x 4 cols per thread
        #pragma unroll
        for (int jj = 0; jj < 64; jj += 4) {
            float4 xv[4], wv[4];
            #pragma unroll
            for (int i = 0; i < 4; ++i)
                xv[i] = *(const float4*)&Xs[rt + 8 * i][jj];
            #pragma unroll
            for (int q = 0; q < 4; ++q)
                wv[q] = *(const float4*)&Ws[jj + q][ct * 4];
            #pragma unroll
            for (int i = 0; i < 4; ++i) {
                acc[i].x += xv[i].x * wv[0].x + xv[i].y * wv[1].x
                          + xv[i].z * wv[2].x + xv[i].w * wv[3].x;
                acc[i].y += xv[i].x * wv[0].y + xv[i].y * wv[1].y
                          + xv[i].z * wv[2].y + xv[i].w * wv[3].y;
                acc[i].z += xv[i].x * wv[0].z + xv[i].y * wv[1].z
                          + xv[i].z * wv[2].z + xv[i].w * wv[3].z;
                acc[i].w += xv[i].x * wv[0].w + xv[i].y * wv[1].w
                          + xv[i].z * wv[2].w + xv[i].w * wv[3].w;
            }
        }
    }

    #pragma unroll
    for (int i = 0; i < 4; ++i) {
        int r = r0 + rt + 8 * i;
        float4 v = acc[i];
        v.x = fminf(fmaxf(v.x, 0.f), 6.f);
        v.y = fminf(fmaxf(v.y, 0.f), 6.f);
        v.z = fminf(fmaxf(v.z, 0.f), 6.f);
        v.w = fminf(fmaxf(v.w, 0.f), 6.f);
        *(float4*)&out[(size_t)r * F + ct * 4] = v;
    }
}

// -------- fused fallback (round-2 kernel, proven correct) --------
__global__ __launch_bounds__(256) void sage_fused(
    const float* __restrict__ feats,
    const float* __restrict__ WT,
    const int*   __restrict__ selfIdx,
    const int*   __restrict__ neighIdx,
    float*       __restrict__ out,
    int nrows)
{
    __shared__ float Xs[BM][68];
    __shared__ float Ws[64][132];
    __shared__ int   sidx[BM];
    __shared__ int   nidx[BM * KNB];

    const int t  = threadIdx.x;
    const int r0 = blockIdx.x * BM;

    if (t < BM)             sidx[t]       = selfIdx[r0 + t];
    if (t < BM * KNB)       nidx[t]       = neighIdx[(size_t)r0 * KNB + t];
    if (t + 256 < BM * KNB) nidx[t + 256] = neighIdx[(size_t)r0 * KNB + t + 256];

    const int ct = (t >> 6) * 8 + (t & 7);
    const int rt = (t >> 3) & 7;
    const int grow = t >> 4;
    const int gc4  = t & 15;

    float4 acc[4];
    #pragma unroll
    for (int i = 0; i < 4; ++i) acc[i] = make_float4(0.f, 0.f, 0.f, 0.f);

    for (int kk = 0; kk < 4; ++kk) {
        __syncthreads();
        {
            const float4* src = (const float4*)(WT + (size_t)kk * 64 * F);
            #pragma unroll
            for (int it = 0; it < 8; ++it) {
                int e4 = t + it * 256;
                int jj = e4 >> 5;
                int o4 = e4 & 31;
                *(float4*)&Ws[jj][o4 * 4] = src[e4];
            }
        }
        if (kk < 2) {
            #pragma unroll
            for (int half = 0; half < 2; ++half) {
                int row = grow + half * 16;
                const float4* src =
                    (const float4*)(feats + (size_t)sidx[row] * F + kk * 64);
                *(float4*)&Xs[row][gc4 * 4] = src[gc4];
            }
        } else {
            #pragma unroll
            for (int half = 0; half < 2; ++half) {
                int row = grow + half * 16;
                float4 a = make_float4(0.f, 0.f, 0.f, 0.f);
                #pragma unroll
                for (int k = 0; k < KNB; ++k) {
                    const float4* src = (const float4*)(
                        feats + (size_t)nidx[row * KNB + k] * F + (kk - 2) * 64);
                    float4 v = src[gc4];
                    a.x += v.x; a.y += v.y; a.z += v.z; a.w += v.w;
                }
                const float inv = 1.0f / (float)KNB;
                a.x *= inv; a.y *= inv; a.z *= inv; a.w *= inv;
                if (isnan(a.x)) a.x = 0.5f;
                if (isnan(a.y)) a.y = 0.5f;
                if (isnan(a.z)) a.z = 0.5f;
                if (isnan(a.w)) a.w = 0.5f;
                *(float4*)&Xs[row][gc4 * 4] = a;
            }
        }
        __syncthreads();

        #pragma unroll
        for (int jj = 0; jj < 64; jj += 4) {
            float4 xv[4], wv[4];
            #pragma unroll
            for (int i = 0; i < 4; ++i)
                xv[i] = *(const float4*)&Xs[rt + 8 * i][jj];
            #pragma unroll
            for (int q = 0; q < 4; ++q)
                wv[q] = *(const float4*)&Ws[jj + q][ct * 4];
            #pragma unroll
            for (int i = 0; i < 4; ++i) {
                acc[i].x += xv[i].x * wv[0].x + xv[i].y * wv[1].x
                          + xv[i].z * wv[2].x + xv[i].w * wv[3].x;
                acc[i].y += xv[i].x * wv[0].y + xv[i].y * wv[1].y
                          + xv[i].z * wv[2].y + xv[i].w * wv[3].y;
                acc[i].z += xv[i].x * wv[0].z + xv[i].y * wv[1].z
                          + xv[i].z * wv[2].z + xv[i].w * wv[3].z;
                acc[i].w += xv[i].x * wv[0].w + xv[i].y * wv[1].w
                          + xv[i].z * wv[2].w + xv[i].w * wv[3].w;
            }
        }
    }

    #pragma unroll
    for (int i = 0; i < 4; ++i) {
        int r = r0 + rt + 8 * i;
        float4 v = acc[i];
        v.x = fminf(fmaxf(v.x, 0.f), 6.f);
        v.y = fminf(fmaxf(v.y, 0.f), 6.f);
        v.z = fminf(fmaxf(v.z, 0.f), 6.f);
        v.w = fminf(fmaxf(v.w, 0.f), 6.f);
        *(float4*)&out[(size_t)r * F + ct * 4] = v;
    }
}

extern "C" void kernel_launch(void* const* d_in, const int* in_sizes, int n_in,
                              void* d_out, int out_size, void* d_ws, size_t ws_size,
                              hipStream_t stream) {
    const float* raw = (const float*)d_in[0];
    const float* W1  = (const float*)d_in[1];
    const float* W2  = (const float*)d_in[2];
    const int*   u1  = (const int*)d_in[3];
    const int*   n1  = (const int*)d_in[4];
    const int*   s2  = (const int*)d_in[5];
    const int*   n2  = (const int*)d_in[6];
    float* out = (float*)d_out;

    const int U1n = in_sizes[3];         // 180224
    const int Bn  = in_sizes[5];         // 16384

    float* ws  = (float*)d_ws;
    float* WT1 = ws;                             // 32768 f
    float* WT2 = WT1 + 256 * 128;                // 32768 f
    float* h1  = WT2 + 256 * 128;                // U1*128 f
    float* ag1 = h1  + (size_t)U1n * F;          // U1*128 f
    float* ag2 = ag1 + (size_t)U1n * F;          // B*128 f

    const size_t need = ((size_t)2 * 256 * 128 + (size_t)U1n * F * 2 + (size_t)Bn * F)
                        * sizeof(float);

    hipLaunchKernelGGL(transpose_w, dim3(128), dim3(256), 0, stream, W1, WT1);
    hipLaunchKernelGGL(transpose_w, dim3(128), dim3(256), 0, stream, W2, WT2);

    if (ws_size >= need) {
        // layer 1
        hipLaunchKernelGGL(gather_mean, dim3(U1n / 8), dim3(256), 0, stream,
                           raw, n1, ag1, U1n);
        hipLaunchKernelGGL(sage_dense, dim3(U1n / BM), dim3(256), 0, stream,
                           raw, ag1, WT1, u1, h1, U1n);
        // layer 2
        hipLaunchKernelGGL(gather_mean, dim3(Bn / 8), dim3(256), 0, stream,
                           h1, n2, ag2, Bn);
        hipLaunchKernelGGL(sage_dense, dim3(Bn / BM), dim3(256), 0, stream,
                           h1, ag2, WT2, s2, out, Bn);
    } else {
        hipLaunchKernelGGL(sage_fused, dim3(U1n / BM), dim3(256), 0, stream,
                           raw, WT1, u1, n1, h1, U1n);
        hipLaunchKernelGGL(sage_fused, dim3(Bn / BM), dim3(256), 0, stream,
                           h1, WT2, s2, n2, out, Bn);
    }
}

// Round 4
// 936.545 us; speedup vs baseline: 1.2095x; 1.2095x over previous
//
#include <hip/hip_runtime.h>
#include <hip/hip_bf16.h>
#include <math.h>

// GraphSAGE 2-layer inference, f32.
// gather_mean: latency-hidden streaming neighbor-mean -> agg in ws.
// sage_dense: [rows x 256] x [256 x 128] GEMM, 8x8 register blocking
//             (BM=128), fused self-gather, coalesced agg reads.

#define F    128
#define KNB  10
#define BM   128

// W [128][256] row-major  ->  WT [256][128] row-major
__global__ __launch_bounds__(256) void transpose_w(const float* __restrict__ W,
                                                   float* __restrict__ WT) {
    int e = blockIdx.x * 256 + threadIdx.x;   // 0 .. 32767
    int o = e >> 8;      // 0..127
    int j = e & 255;     // 0..255
    WT[j * F + o] = W[e];
}

// agg[row][:] = mean_k feats[nidx[row][k]][:]   (isnan -> 0.5 parity)
// 8 rows/block, 32 lanes/row (float4 each). All 10 gathers in flight.
__global__ __launch_bounds__(256) void gather_mean(
    const float* __restrict__ feats,      // [nsrc][128]
    const int*   __restrict__ neighIdx,   // [nrows][10]
    float*       __restrict__ agg,        // [nrows][128]
    int nrows)
{
    const int t    = threadIdx.x;
    const int row  = blockIdx.x * 8 + (t >> 5);
    const int lane = t & 31;
    if (row >= nrows) return;

    const int* nb = neighIdx + (size_t)row * KNB;
    int n0 = nb[0], n1 = nb[1], n2 = nb[2], n3 = nb[3], n4 = nb[4];
    int n5 = nb[5], n6 = nb[6], n7 = nb[7], n8 = nb[8], n9 = nb[9];

    const size_t c = (size_t)lane * 4;
    float4 v0 = *(const float4*)(feats + (size_t)n0 * F + c);
    float4 v1 = *(const float4*)(feats + (size_t)n1 * F + c);
    float4 v2 = *(const float4*)(feats + (size_t)n2 * F + c);
    float4 v3 = *(const float4*)(feats + (size_t)n3 * F + c);
    float4 v4 = *(const float4*)(feats + (size_t)n4 * F + c);
    float4 v5 = *(const float4*)(feats + (size_t)n5 * F + c);
    float4 v6 = *(const float4*)(feats + (size_t)n6 * F + c);
    float4 v7 = *(const float4*)(feats + (size_t)n7 * F + c);
    float4 v8 = *(const float4*)(feats + (size_t)n8 * F + c);
    float4 v9 = *(const float4*)(feats + (size_t)n9 * F + c);

    float4 s;
    s.x = ((v0.x + v1.x) + (v2.x + v3.x)) + ((v4.x + v5.x) + (v6.x + v7.x)) + (v8.x + v9.x);
    s.y = ((v0.y + v1.y) + (v2.y + v3.y)) + ((v4.y + v5.y) + (v6.y + v7.y)) + (v8.y + v9.y);
    s.z = ((v0.z + v1.z) + (v2.z + v3.z)) + ((v4.z + v5.z) + (v6.z + v7.z)) + (v8.z + v9.z);
    s.w = ((v0.w + v1.w) + (v2.w + v3.w)) + ((v4.w + v5.w) + (v6.w + v7.w)) + (v8.w + v9.w);
    const float inv = 1.0f / (float)KNB;
    s.x *= inv; s.y *= inv; s.z *= inv; s.w *= inv;
    if (isnan(s.x)) s.x = 0.5f;
    if (isnan(s.y)) s.y = 0.5f;
    if (isnan(s.z)) s.z = 0.5f;
    if (isnan(s.w)) s.w = 0.5f;

    *(float4*)(agg + (size_t)row * F + c) = s;
}

// out[r][o] = relu6( sum_j [self | agg][r][j] * WT[j][o] )
// BM=128 rows/block, 256 threads, 8 rows x 8 cols per thread.
__global__ __launch_bounds__(256, 2) void sage_dense(
    const float* __restrict__ feats,     // self source [nsrc][128]
    const float* __restrict__ agg,       // [nrows][128] precomputed mean
    const float* __restrict__ WT,        // [256][128]
    const int*   __restrict__ selfIdx,   // [nrows]
    float*       __restrict__ out,       // [nrows][128]
    int nrows)
{
    __shared__ float Xs[BM][68];         // 64-col K-chunk of X, row stride 68 (+4 banks/row)
    __shared__ float Ws[64][132];        // WT chunk
    __shared__ int   sidx[BM];

    const int t  = threadIdx.x;
    const int r0 = blockIdx.x * BM;

    if (t < BM) sidx[t] = selfIdx[r0 + t];

    const int ctg = t & 15;              // cols: ctg*4..+3 and ctg*4+64..+3
    const int rt  = t >> 4;              // rows: rt, rt+16, ..., rt+112

    const int grow = t >> 4;             // stage: base row (0..15), +16 per iter
    const int gc4  = t & 15;             // stage: float4 slot within 64-col chunk

    float4 accA[8], accB[8];
    #pragma unroll
    for (int i = 0; i < 8; ++i) {
        accA[i] = make_float4(0.f, 0.f, 0.f, 0.f);
        accB[i] = make_float4(0.f, 0.f, 0.f, 0.f);
    }

    for (int kk = 0; kk < 4; ++kk) {
        __syncthreads();   // covers sidx on iter 0; protects LDS reuse after

        // ---- stage WT chunk: Ws[jj][o] = WT[kk*64 + jj][o], 2048 float4s ----
        {
            const float4* src = (const float4*)(WT + (size_t)kk * 64 * F);
            #pragma unroll
            for (int it = 0; it < 8; ++it) {
                int e4 = t + it * 256;           // 0..2047 == jj*32 + o4
                int jj = e4 >> 5;
                int o4 = e4 & 31;
                *(float4*)&Ws[jj][o4 * 4] = src[e4];
            }
        }

        // ---- stage X chunk: Xs[row][c] = X[r0+row][kk*64 + c], 2048 float4s ----
        if (kk < 2) {
            #pragma unroll
            for (int it = 0; it < 8; ++it) {
                int row = grow + it * 16;
                const float4* src =
                    (const float4*)(feats + (size_t)sidx[row] * F + kk * 64);
                *(float4*)&Xs[row][gc4 * 4] = src[gc4];
            }
        } else {
            #pragma unroll
            for (int it = 0; it < 8; ++it) {
                int row = grow + it * 16;
                const float4* src =
                    (const float4*)(agg + (size_t)(r0 + row) * F + (kk - 2) * 64);
                *(float4*)&Xs[row][gc4 * 4] = src[gc4];
            }
        }
        __syncthreads();

        // ---- register-blocked GEMM: 8 rows x 8 cols per thread ----
        #pragma unroll 8
        for (int jj = 0; jj < 64; jj += 4) {
            float4 xv[8], wA[4], wB[4];
            #pragma unroll
            for (int q = 0; q < 4; ++q) {
                wA[q] = *(const float4*)&Ws[jj + q][ctg * 4];
                wB[q] = *(const float4*)&Ws[jj + q][ctg * 4 + 64];
            }
            #pragma unroll
            for (int i = 0; i < 8; ++i)
                xv[i] = *(const float4*)&Xs[rt + 16 * i][jj];
            #pragma unroll
            for (int i = 0; i < 8; ++i) {
                accA[i].x += xv[i].x * wA[0].x + xv[i].y * wA[1].x
                           + xv[i].z * wA[2].x + xv[i].w * wA[3].x;
                accA[i].y += xv[i].x * wA[0].y + xv[i].y * wA[1].y
                           + xv[i].z * wA[2].y + xv[i].w * wA[3].y;
                accA[i].z += xv[i].x * wA[0].z + xv[i].y * wA[1].z
                           + xv[i].z * wA[2].z + xv[i].w * wA[3].z;
                accA[i].w += xv[i].x * wA[0].w + xv[i].y * wA[1].w
                           + xv[i].z * wA[2].w + xv[i].w * wA[3].w;
                accB[i].x += xv[i].x * wB[0].x + xv[i].y * wB[1].x
                           + xv[i].z * wB[2].x + xv[i].w * wB[3].x;
                accB[i].y += xv[i].x * wB[0].y + xv[i].y * wB[1].y
                           + xv[i].z * wB[2].y + xv[i].w * wB[3].y;
                accB[i].z += xv[i].x * wB[0].z + xv[i].y * wB[1].z
                           + xv[i].z * wB[2].z + xv[i].w * wB[3].z;
                accB[i].w += xv[i].x * wB[0].w + xv[i].y * wB[1].w
                           + xv[i].z * wB[2].w + xv[i].w * wB[3].w;
            }
        }
    }

    // ---- epilogue: relu6 + float4 stores ----
    #pragma unroll
    for (int i = 0; i < 8; ++i) {
        int r = r0 + rt + 16 * i;
        float4 v = accA[i];
        v.x = fminf(fmaxf(v.x, 0.f), 6.f);
        v.y = fminf(fmaxf(v.y, 0.f), 6.f);
        v.z = fminf(fmaxf(v.z, 0.f), 6.f);
        v.w = fminf(fmaxf(v.w, 0.f), 6.f);
        *(float4*)&out[(size_t)r * F + ctg * 4] = v;
        float4 u = accB[i];
        u.x = fminf(fmaxf(u.x, 0.f), 6.f);
        u.y = fminf(fmaxf(u.y, 0.f), 6.f);
        u.z = fminf(fmaxf(u.z, 0.f), 6.f);
        u.w = fminf(fmaxf(u.w, 0.f), 6.f);
        *(float4*)&out[(size_t)r * F + ctg * 4 + 64] = u;
    }
}

extern "C" void kernel_launch(void* const* d_in, const int* in_sizes, int n_in,
                              void* d_out, int out_size, void* d_ws, size_t ws_size,
                              hipStream_t stream) {
    const float* raw = (const float*)d_in[0];
    const float* W1  = (const float*)d_in[1];
    const float* W2  = (const float*)d_in[2];
    const int*   u1  = (const int*)d_in[3];
    const int*   n1  = (const int*)d_in[4];
    const int*   s2  = (const int*)d_in[5];
    const int*   n2  = (const int*)d_in[6];
    float* out = (float*)d_out;

    const int U1n = in_sizes[3];         // 180224
    const int Bn  = in_sizes[5];         // 16384

    float* ws  = (float*)d_ws;
    float* WT1 = ws;                             // 32768 f
    float* WT2 = WT1 + 256 * 128;                // 32768 f
    float* h1  = WT2 + 256 * 128;                // U1*128 f
    float* ag1 = h1  + (size_t)U1n * F;          // U1*128 f
    float* ag2 = ag1 + (size_t)U1n * F;          // B*128 f

    hipLaunchKernelGGL(transpose_w, dim3(128), dim3(256), 0, stream, W1, WT1);
    hipLaunchKernelGGL(transpose_w, dim3(128), dim3(256), 0, stream, W2, WT2);

    // layer 1
    hipLaunchKernelGGL(gather_mean, dim3(U1n / 8), dim3(256), 0, stream,
                       raw, n1, ag1, U1n);
    hipLaunchKernelGGL(sage_dense, dim3(U1n / BM), dim3(256), 0, stream,
                       raw, ag1, WT1, u1, h1, U1n);
    // layer 2
    hipLaunchKernelGGL(gather_mean, dim3(Bn / 8), dim3(256), 0, stream,
                       h1, n2, ag2, Bn);
    hipLaunchKernelGGL(sage_dense, dim3(Bn / BM), dim3(256), 0, stream,
                       h1, ag2, WT2, s2, out, Bn);
}